// Round 7
// baseline (112.689 us; speedup 1.0000x reference)
//
#include <hip/hip_runtime.h>

// B=32, T_IN=12, H=64, W=64, C_IN=4, T_OUT=12, C_OUT=4, O=48, K=8, S=4
// NH=NW=15, L=225. DEC_K=25, p=12 -> trend[t] = A + t*D (affine in t).
//
// Per (batch, residue class (rh,rw)) block, the problem is a GEMM:
//   W_cls[192 x 64] . X[64 x 256 pixels]   (K=57 used, padded to 64)
// A-operand = weights (m = to*16 + c*4 + combo), B-operand = pixels.
// D layout: col=lane&15 = pixel-in-group, row=quad*4+reg -> c=quad, combo=reg
// => masked fold-sum over combos is 4 in-lane selects + 3 adds (no shfl).

typedef _Float16 h2 __attribute__((ext_vector_type(2)));
typedef _Float16 f16x8 __attribute__((ext_vector_type(8)));
typedef float f32x4 __attribute__((ext_vector_type(4)));
union F4F16 { float4 f4; f16x8 h8; };

// ---- pack: fragments direct from w_s/w_t.
// PWF[((cls*12+to)*2+ks)*64 + L] = 16B frag: rows k=ks*32+quad*8+j, col
// m16 = L&15 = c*4+combo.  k: 0..47 w_s(t=k>>2,cin=k&3); 48..51 W0[cin];
// 52..55 W1[cin]; 56 bias; 57..63 zero.  (W0=sum_t(w_t-w_s), W1=sum_t t*(..))
__global__ __launch_bounds__(64) void pack_frags(const float* __restrict__ w_s,
                                                 const float* __restrict__ b_s,
                                                 const float* __restrict__ w_t,
                                                 const float* __restrict__ b_t,
                                                 float4* __restrict__ PWF) {
    int blk = blockIdx.x;  // cls*12 + to, 192 blocks
    int cls = blk / 12;
    int to = blk % 12;
    int L = threadIdx.x;
    int m16 = L & 15, quad = L >> 4;
    int c = m16 >> 2, r = m16 & 3;
    int o = to * 4 + c;
    int rh = cls >> 2, rw = cls & 3;
    int s = (rh + 4 * (r >> 1)) * 8 + (rw + 4 * (r & 1));
    const float* Wsb = w_s + (size_t)o * 3072 + s;  // w_s[o,.,.,s], step 64 per k
    const float* Wtb = w_t + (size_t)o * 3072 + s;
#pragma unroll
    for (int ks = 0; ks < 2; ++ks) {
        F4F16 u;
#pragma unroll
        for (int j = 0; j < 8; ++j) {
            int k = ks * 32 + quad * 8 + j;
            float val;
            if (k < 48) {
                val = Wsb[k * 64];
            } else if (k < 56) {
                int c2 = k & 3;
                bool isW1 = (k & 4) != 0;
                float acc = 0.f;
                for (int t = 0; t < 12; ++t) {
                    float d = Wtb[(t * 4 + c2) * 64] - Wsb[(t * 4 + c2) * 64];
                    acc += isW1 ? (float)t * d : d;
                }
                val = acc;
            } else if (k == 56) {
                val = b_s[o * 64 + s] + b_t[o * 64 + s];
            } else {
                val = 0.f;
            }
            u.h8[j] = (_Float16)val;
        }
        PWF[((size_t)blk * 2 + ks) * 64 + L] = u.f4;
    }
}

// ---- main: grid 512 = 32 b x 16 cls (2 blocks/CU), 256 threads (4 waves).
__global__ __launch_bounds__(256, 2) void dlinear_mfma(const float* __restrict__ x,
                                                       const float4* __restrict__ PWF,
                                                       float* __restrict__ out) {
    __shared__ float4 As[256 * 9];              // 36864 B: pixel rows, 144 B stride
    __shared__ __align__(16) float Es[4][256];  // 4 KB: per-wave epilogue bounce
    int tid = threadIdx.x;
    int wv = tid >> 6, L = tid & 63;
    int cls = blockIdx.x & 15;
    int bb = blockIdx.x >> 4;
    int rh = cls >> 2, rw = cls & 3;

    // A-operand (weights) persistent in VGPRs: 24 coalesced 16B loads, L3-hot.
    f16x8 wf[12][2];
#pragma unroll
    for (int to = 0; to < 12; ++to)
#pragma unroll
        for (int ks = 0; ks < 2; ++ks) {
            F4F16 u;
            u.f4 = PWF[((size_t)(cls * 12 + to) * 2 + ks) * 64 + L];
            wf[to][ks] = u.h8;
        }

    // Phase 1: per-pixel X -> LDS row (thread = pixel p = hh*16+ww).
    int hh = tid >> 4, wwp = tid & 15;
    int h = 4 * hh + rh, wcol0 = 4 * wwp + rw;
    const float4* xb = (const float4*)x + (size_t)bb * 12 * 4096 + h * 64 + wcol0;

    h2 X2[32] __attribute__((aligned(16)));
    {
        float sx = 0.f, sy = 0.f, sz = 0.f, sw = 0.f;
        float4 first, last;
#pragma unroll
        for (int t = 0; t < 12; ++t) {
            float4 v = xb[t * 4096];
            if (t == 0) first = v;
            if (t == 11) last = v;
            h2 a, b;
            a[0] = (_Float16)v.x; a[1] = (_Float16)v.y;
            b[0] = (_Float16)v.z; b[1] = (_Float16)v.w;
            X2[2 * t] = a;
            X2[2 * t + 1] = b;
            sx += v.x; sy += v.y; sz += v.z; sw += v.w;
        }
        const float inv25 = 1.f / 25.f;
        float A0 = (sx + 12.f * first.x + last.x) * inv25;
        float A1 = (sy + 12.f * first.y + last.y) * inv25;
        float A2 = (sz + 12.f * first.z + last.z) * inv25;
        float A3 = (sw + 12.f * first.w + last.w) * inv25;
        float D0 = (last.x - first.x) * inv25;
        float D1 = (last.y - first.y) * inv25;
        float D2 = (last.z - first.z) * inv25;
        float D3 = (last.w - first.w) * inv25;
        h2 t0, t1, t2, t3, t4, z;
        t0[0] = (_Float16)A0; t0[1] = (_Float16)A1;
        t1[0] = (_Float16)A2; t1[1] = (_Float16)A3;
        t2[0] = (_Float16)D0; t2[1] = (_Float16)D1;
        t3[0] = (_Float16)D2; t3[1] = (_Float16)D3;
        t4[0] = (_Float16)1.f; t4[1] = (_Float16)0.f;
        z[0] = (_Float16)0.f; z[1] = (_Float16)0.f;
        X2[24] = t0; X2[25] = t1; X2[26] = t2; X2[27] = t3;
        X2[28] = t4; X2[29] = z; X2[30] = z; X2[31] = z;
    }
#pragma unroll
    for (int j = 0; j < 8; ++j) As[tid * 9 + j] = ((float4*)X2)[j];
    __syncthreads();

    // Phase 2: B-operand (pixel) fragments, wave's 4 groups of 16 pixels.
    int quad = L >> 4, nlane = L & 15;
    f16x8 pf[4][2];
#pragma unroll
    for (int g = 0; g < 4; ++g) {
        int p = wv * 64 + g * 16 + nlane;
#pragma unroll
        for (int ks = 0; ks < 2; ++ks) {
            F4F16 u;
            u.f4 = As[p * 9 + ks * 4 + quad];
            pf[g][ks] = u.h8;
        }
    }

    // Phase 3: MFMA + in-lane masked combo sum + LDS bounce + float4 stores.
    // regs: combo = reg (di=reg>>1, dj=reg&1); c = quad; pixel = g*16+nlane.
    bool okw0 = nlane <= 14, okw1 = nlane >= 1;  // dj=0 / dj=1 (per-lane, ww)
    float4* ob = (float4*)out + (size_t)bb * 12 * 4096;
    int rdpix = wv * 64 + L;                     // pixel this lane stores
    int st_hh = rdpix >> 4, st_ww = rdpix & 15;
    float4* stp = ob + (4 * st_hh + rh) * 64 + (4 * st_ww + rw);

#pragma unroll
    for (int to = 0; to < 12; ++to) {
#pragma unroll
        for (int g = 0; g < 4; ++g) {
            f32x4 d = {0.f, 0.f, 0.f, 0.f};
            d = __builtin_amdgcn_mfma_f32_16x16x32_f16(wf[to][0], pf[g][0], d, 0, 0, 0);
            d = __builtin_amdgcn_mfma_f32_16x16x32_f16(wf[to][1], pf[g][1], d, 0, 0, 0);
            int hq = wv * 4 + g;  // hh of these pixels (wave-uniform)
            bool okh0 = hq <= 14, okh1 = hq >= 1;  // di=0 / di=1
            float v = ((okh0 && okw0) ? d[0] : 0.f)
                    + ((okh0 && okw1) ? d[1] : 0.f)
                    + ((okh1 && okw0) ? d[2] : 0.f)
                    + ((okh1 && okw1) ? d[3] : 0.f);
            Es[wv][g * 64 + nlane * 4 + quad] = v;  // [pixel][c], 2-way banks
        }
        // wave-coherent LDS (in-order pipe): read back per-pixel float4
        float4 r = *(const float4*)&Es[wv][4 * L];
        stp[to * 4096] = r;
    }
}

extern "C" void kernel_launch(void* const* d_in, const int* in_sizes, int n_in,
                              void* d_out, int out_size, void* d_ws, size_t ws_size,
                              hipStream_t stream) {
    const float* x = (const float*)d_in[0];
    const float* w_s = (const float*)d_in[1];
    const float* b_s = (const float*)d_in[2];
    const float* w_t = (const float*)d_in[3];
    const float* b_t = (const float*)d_in[4];
    float* out = (float*)d_out;
    float4* PWF = (float4*)d_ws;  // 192*2*64*16 = 393216 B

    pack_frags<<<192, 64, 0, stream>>>(w_s, b_s, w_t, b_t, PWF);
    dlinear_mfma<<<32 * 16, 256, 0, stream>>>(x, PWF, out);
}

// Round 8
// 107.344 us; speedup vs baseline: 1.0498x; 1.0498x over previous
//
#include <hip/hip_runtime.h>

// B=32, T_IN=12, H=64, W=64, C_IN=4, T_OUT=12, C_OUT=4, O=48, K=8, S=4
// NH=NW=15, L=225. DEC_K=25, p=12 -> trend[t] = A + t*D (affine in t).
//
// GEMM per class: W_cls[192 x 64] (A-op) . X[64 x pixels] (B-op).
// k: 0..47 w_s(t=k>>2,cin=k&3); 48..51 W0[cin]; 52..55 W1[cin]; 56 bias; pad 0.
// A-frag row m16 = c*4 + combo r (di=r>>1, dj=r&1, s=(rh+4di)*8+(rw+4dj)).
// D: row = quad*4+reg -> (c=quad, combo=reg); col = nlane -> pixel.
//
// Main block = (b, rh, w-half): 16 contiguous-in-memory rows (h=4a+rh) x 32
// cols -> x loads and out stores are 512B contiguous runs (no granule waste).
// 8 waves: wave wv handles class rw=wv&3, groups G=(wv>>2)*4..+3 (group =
// rows {2G,2G+1} x 8 cols of its class, nlane = rowparity*8 + ci).

typedef _Float16 h2 __attribute__((ext_vector_type(2)));
typedef _Float16 f16x8 __attribute__((ext_vector_type(8)));
typedef float f32x4 __attribute__((ext_vector_type(4)));
union F2H8 { struct { float2 lo, hi; } f; f16x8 h8; };
union HU { _Float16 h; unsigned short u; };

// ---- pack: 192 blocks (cls*12+to) x 256 threads.
// Stage A (64 threads): W0/W1 table -> LDS. Stage B (all): emit f16 frags,
// 8 B per thread: PWF[((blk*2+ks)*64+L)*16 + jh*8] = halves j=jh*4..jh*4+3.
__global__ __launch_bounds__(256) void pack_frags(const float* __restrict__ w_s,
                                                  const float* __restrict__ b_s,
                                                  const float* __restrict__ w_t,
                                                  const float* __restrict__ b_t,
                                                  uint2* __restrict__ PWF) {
    __shared__ float W01[2][16][4];
    int blk = blockIdx.x;
    int cls = blk / 12, to = blk % 12;
    int rh = cls >> 2, rw = cls & 3;
    int tid = threadIdx.x;

    if (tid < 64) {
        int m16 = tid >> 2, cin = tid & 3;
        int c = m16 >> 2, rr = m16 & 3;
        int o = to * 4 + c;
        int s = (rh + 4 * (rr >> 1)) * 8 + (rw + 4 * (rr & 1));
        float a0 = 0.f, a1 = 0.f;
#pragma unroll
        for (int t = 0; t < 12; ++t) {
            int base = ((o * 12 + t) * 4 + cin) * 64 + s;
            float d = w_t[base] - w_s[base];
            a0 += d;
            a1 += (float)t * d;
        }
        W01[0][m16][cin] = a0;
        W01[1][m16][cin] = a1;
    }
    __syncthreads();

    int ks = tid >> 7, jh = (tid >> 6) & 1, L = tid & 63;
    int quad = L >> 4, m16 = L & 15;
    int c = m16 >> 2, rr = m16 & 3;
    int o = to * 4 + c;
    int s = (rh + 4 * (rr >> 1)) * 8 + (rw + 4 * (rr & 1));
    unsigned short us[4];
#pragma unroll
    for (int j4 = 0; j4 < 4; ++j4) {
        int j = jh * 4 + j4;
        int k = ks * 32 + quad * 8 + j;
        float val;
        if (k < 48) {
            val = w_s[((o * 12 + (k >> 2)) * 4 + (k & 3)) * 64 + s];
        } else if (k < 56) {
            val = W01[(k >> 2) & 1][m16][k & 3];
        } else if (k == 56) {
            val = b_s[o * 64 + s] + b_t[o * 64 + s];
        } else {
            val = 0.f;
        }
        HU hu;
        hu.h = (_Float16)val;
        us[j4] = hu.u;
    }
    uint2 pk;
    pk.x = (unsigned)us[0] | ((unsigned)us[1] << 16);
    pk.y = (unsigned)us[2] | ((unsigned)us[3] << 16);
    PWF[((size_t)(blk * 2 + ks) * 64 + L) * 2 + jh] = pk;
}

// ---- main: grid 256 = 32 b x 4 rh x 2 w-half; 512 threads (8 waves).
__global__ __launch_bounds__(512, 4) void dlinear_mfma(const float* __restrict__ x,
                                                       const float4* __restrict__ PWF,
                                                       float* __restrict__ out) {
    __shared__ __align__(16) float2 As2[512 * 17];  // 69632 B: 128B X-row + 8B pad
    __shared__ float Es[512 * 5];                   // 10240 B: [pixel][c] pad-5
    int tid = threadIdx.x;
    int wv = tid >> 6, L = tid & 63;
    unsigned bx = blockIdx.x;
    int wh = bx & 1, rh = (bx >> 1) & 3;
    int bb = bx >> 3;

    // Phase 1: thread = block-local pixel p (contiguous): row a=p>>5, col cw=p&31.
    int a = tid >> 5, cw = tid & 31;
    int h = 4 * a + rh, wimg = wh * 32 + cw;
    const float4* xb = (const float4*)x + (size_t)bb * 12 * 4096 + h * 64 + wimg;

    h2 X2[32] __attribute__((aligned(16)));
    {
        float sx = 0.f, sy = 0.f, sz = 0.f, sw = 0.f;
        float4 first, last;
#pragma unroll
        for (int t = 0; t < 12; ++t) {
            float4 v = xb[t * 4096];
            if (t == 0) first = v;
            if (t == 11) last = v;
            h2 aa, bbh;
            aa[0] = (_Float16)v.x; aa[1] = (_Float16)v.y;
            bbh[0] = (_Float16)v.z; bbh[1] = (_Float16)v.w;
            X2[2 * t] = aa;
            X2[2 * t + 1] = bbh;
            sx += v.x; sy += v.y; sz += v.z; sw += v.w;
        }
        const float inv25 = 1.f / 25.f;
        float A0 = (sx + 12.f * first.x + last.x) * inv25;
        float A1 = (sy + 12.f * first.y + last.y) * inv25;
        float A2 = (sz + 12.f * first.z + last.z) * inv25;
        float A3 = (sw + 12.f * first.w + last.w) * inv25;
        float D0 = (last.x - first.x) * inv25;
        float D1 = (last.y - first.y) * inv25;
        float D2 = (last.z - first.z) * inv25;
        float D3 = (last.w - first.w) * inv25;
        h2 t0, t1, t2, t3, t4, z;
        t0[0] = (_Float16)A0; t0[1] = (_Float16)A1;
        t1[0] = (_Float16)A2; t1[1] = (_Float16)A3;
        t2[0] = (_Float16)D0; t2[1] = (_Float16)D1;
        t3[0] = (_Float16)D2; t3[1] = (_Float16)D3;
        t4[0] = (_Float16)1.f; t4[1] = (_Float16)0.f;
        z[0] = (_Float16)0.f; z[1] = (_Float16)0.f;
        X2[24] = t0; X2[25] = t1; X2[26] = t2; X2[27] = t3;
        X2[28] = t4; X2[29] = z; X2[30] = z; X2[31] = z;
    }
    {
        const float2* xf2 = (const float2*)X2;
#pragma unroll
        for (int j = 0; j < 16; ++j) As2[17 * tid + j] = xf2[j];
    }
    __syncthreads();

    // Phase 2: B-operand (pixel) fragments. Wave: class rcls, groups ghalf*4..+3.
    int quad = L >> 4, nlane = L & 15;
    int rcls = wv & 3, ghalf = wv >> 2;
    int cls = rh * 4 + rcls;
    f16x8 pf[4][2];
#pragma unroll
    for (int g = 0; g < 4; ++g) {
        int G = ghalf * 4 + g;
        int p = 64 * G + 32 * (nlane >> 3) + 4 * (nlane & 7) + rcls;
        int base = 17 * p;
#pragma unroll
        for (int ks = 0; ks < 2; ++ks) {
            F2H8 u;
            u.f.lo = As2[base + ks * 8 + quad * 2];
            u.f.hi = As2[base + ks * 8 + quad * 2 + 1];
            pf[g][ks] = u.h8;
        }
    }

    // Per-lane fold masks (pixel of this lane in group g: hh=2G+rp, ww=wh*8+ci)
    int rp = nlane >> 3, ci = nlane & 7;
    int wwp = wh * 8 + ci;
    bool okw0 = wwp <= 14, okw1 = wwp >= 1;

    float4* ob = (float4*)out + (size_t)bb * 12 * 4096;
    float4* stp = ob + h * 64 + wimg;  // this thread's store pixel (=p=tid)

    // Phase 3: to in halves of 6 (wf = 48 VGPRs), per to: MFMA -> Es -> store.
#pragma unroll 1
    for (int toh = 0; toh < 2; ++toh) {
        f16x8 wf[6][2];
#pragma unroll
        for (int tt = 0; tt < 6; ++tt)
#pragma unroll
            for (int ks = 0; ks < 2; ++ks) {
                F2H8 u;
                const float4 v = PWF[((size_t)(cls * 12 + toh * 6 + tt) * 2 + ks) * 64 + L];
                u.f.lo = make_float2(v.x, v.y);
                u.f.hi = make_float2(v.z, v.w);
                wf[tt][ks] = u.h8;
            }
#pragma unroll 1
        for (int tt = 0; tt < 6; ++tt) {
            int to = toh * 6 + tt;
#pragma unroll
            for (int g = 0; g < 4; ++g) {
                int G = ghalf * 4 + g;
                f32x4 d = {0.f, 0.f, 0.f, 0.f};
                d = __builtin_amdgcn_mfma_f32_16x16x32_f16(wf[tt][0], pf[g][0], d, 0, 0, 0);
                d = __builtin_amdgcn_mfma_f32_16x16x32_f16(wf[tt][1], pf[g][1], d, 0, 0, 0);
                int hhl = 2 * G + rp;
                bool okh0 = hhl <= 14, okh1 = hhl >= 1;
                float v = ((okh0 && okw0) ? d[0] : 0.f)
                        + ((okh0 && okw1) ? d[1] : 0.f)
                        + ((okh1 && okw0) ? d[2] : 0.f)
                        + ((okh1 && okw1) ? d[3] : 0.f);
                int p = 64 * G + 32 * rp + 4 * ci + rcls;
                Es[5 * p + quad] = v;
            }
            __syncthreads();
            float4 r;
            r.x = Es[5 * tid + 0];
            r.y = Es[5 * tid + 1];
            r.z = Es[5 * tid + 2];
            r.w = Es[5 * tid + 3];
            stp[to * 4096] = r;
            __syncthreads();
        }
    }
}

extern "C" void kernel_launch(void* const* d_in, const int* in_sizes, int n_in,
                              void* d_out, int out_size, void* d_ws, size_t ws_size,
                              hipStream_t stream) {
    const float* x = (const float*)d_in[0];
    const float* w_s = (const float*)d_in[1];
    const float* b_s = (const float*)d_in[2];
    const float* w_t = (const float*)d_in[3];
    const float* b_t = (const float*)d_in[4];
    float* out = (float*)d_out;
    void* PWF = d_ws;  // 192*2*64*16 = 393216 B

    pack_frags<<<192, 256, 0, stream>>>(w_s, b_s, w_t, b_t, (uint2*)PWF);
    dlinear_mfma<<<32 * 4 * 2, 512, 0, stream>>>(x, (const float4*)PWF, out);
}

// Round 9
// 98.559 us; speedup vs baseline: 1.1434x; 1.0891x over previous
//
#include <hip/hip_runtime.h>

// B=32, T_IN=12, H=64, W=64, C_IN=4, T_OUT=12, C_OUT=4, O=48, K=8, S=4
// NH=NW=15, L=225. DEC_K=25, p=12 -> trend[t] = A + t*D (affine in t).
//
// GEMM per class: W_cls[192 x 64] (A-op) . X[64 x pixels] (B-op).
// k: 0..47 w_s(t=k>>2,cin=k&3); 48..51 W0[cin]; 52..55 W1[cin]; 56 bias; pad 0.
// A-frag row m16 = c*4 + combo r (di=r>>1, dj=r&1, s=(rh+4di)*8+(rw+4dj)).
// D: row = quad*4+reg -> (c=quad, combo=reg); col = nlane -> pixel.
//
// Main block = (b, rh, w-half): 16 contiguous-in-memory rows (h=4a+rh) x 32
// cols -> x loads contiguous 512B runs. 8 waves: wave wv = class rcls=wv&3,
// groups G=(wv>>2)*4..+3. Epilogue: in-lane masked combo fold + DIRECT dword
// stores (no LDS bounce, no barriers): the 4 rcls waves of a block jointly
// cover every dword of the row span, so L2 merges to ~1x HBM write traffic.

typedef _Float16 h2 __attribute__((ext_vector_type(2)));
typedef _Float16 f16x8 __attribute__((ext_vector_type(8)));
typedef float f32x4 __attribute__((ext_vector_type(4)));
union F2H8 { struct { float2 lo, hi; } f; f16x8 h8; };
union HU { _Float16 h; unsigned short u; };

// ---- pack: 192 blocks (cls*12+to) x 256 threads.
__global__ __launch_bounds__(256) void pack_frags(const float* __restrict__ w_s,
                                                  const float* __restrict__ b_s,
                                                  const float* __restrict__ w_t,
                                                  const float* __restrict__ b_t,
                                                  uint2* __restrict__ PWF) {
    __shared__ float W01[2][16][4];
    int blk = blockIdx.x;
    int cls = blk / 12, to = blk % 12;
    int rh = cls >> 2, rw = cls & 3;
    int tid = threadIdx.x;

    if (tid < 64) {
        int m16 = tid >> 2, cin = tid & 3;
        int c = m16 >> 2, rr = m16 & 3;
        int o = to * 4 + c;
        int s = (rh + 4 * (rr >> 1)) * 8 + (rw + 4 * (rr & 1));
        float a0 = 0.f, a1 = 0.f;
#pragma unroll
        for (int t = 0; t < 12; ++t) {
            int base = ((o * 12 + t) * 4 + cin) * 64 + s;
            float d = w_t[base] - w_s[base];
            a0 += d;
            a1 += (float)t * d;
        }
        W01[0][m16][cin] = a0;
        W01[1][m16][cin] = a1;
    }
    __syncthreads();

    int ks = tid >> 7, jh = (tid >> 6) & 1, L = tid & 63;
    int quad = L >> 4, m16 = L & 15;
    int c = m16 >> 2, rr = m16 & 3;
    int o = to * 4 + c;
    int s = (rh + 4 * (rr >> 1)) * 8 + (rw + 4 * (rr & 1));
    unsigned short us[4];
#pragma unroll
    for (int j4 = 0; j4 < 4; ++j4) {
        int j = jh * 4 + j4;
        int k = ks * 32 + quad * 8 + j;
        float val;
        if (k < 48) {
            val = w_s[((o * 12 + (k >> 2)) * 4 + (k & 3)) * 64 + s];
        } else if (k < 56) {
            val = W01[(k >> 2) & 1][m16][k & 3];
        } else if (k == 56) {
            val = b_s[o * 64 + s] + b_t[o * 64 + s];
        } else {
            val = 0.f;
        }
        HU hu;
        hu.h = (_Float16)val;
        us[j4] = hu.u;
    }
    uint2 pk;
    pk.x = (unsigned)us[0] | ((unsigned)us[1] << 16);
    pk.y = (unsigned)us[2] | ((unsigned)us[3] << 16);
    PWF[((size_t)(blk * 2 + ks) * 64 + L) * 2 + jh] = pk;
}

// ---- main: grid 256 = 32 b x 4 rh x 2 w-half; 512 threads (8 waves).
__global__ __launch_bounds__(512, 4) void dlinear_mfma(const float* __restrict__ x,
                                                       const float4* __restrict__ PWF,
                                                       float* __restrict__ out) {
    __shared__ __align__(16) float2 As2[512 * 17];  // 69632 B: 128B X-row + 8B pad
    int tid = threadIdx.x;
    int wv = tid >> 6, L = tid & 63;
    unsigned bx = blockIdx.x;
    int wh = bx & 1, rh = (bx >> 1) & 3;
    int bb = bx >> 3;

    // Phase 1: thread = block-local pixel p: row a=p>>5 (h=4a+rh), col cw=p&31.
    int a = tid >> 5, cw = tid & 31;
    int h = 4 * a + rh, wimg = wh * 32 + cw;
    const float4* xb = (const float4*)x + (size_t)bb * 12 * 4096 + h * 64 + wimg;

    h2 X2[32] __attribute__((aligned(16)));
    {
        float sx = 0.f, sy = 0.f, sz = 0.f, sw = 0.f;
        float4 first, last;
#pragma unroll
        for (int t = 0; t < 12; ++t) {
            float4 v = xb[t * 4096];
            if (t == 0) first = v;
            if (t == 11) last = v;
            h2 aa, bbh;
            aa[0] = (_Float16)v.x; aa[1] = (_Float16)v.y;
            bbh[0] = (_Float16)v.z; bbh[1] = (_Float16)v.w;
            X2[2 * t] = aa;
            X2[2 * t + 1] = bbh;
            sx += v.x; sy += v.y; sz += v.z; sw += v.w;
        }
        const float inv25 = 1.f / 25.f;
        float A0 = (sx + 12.f * first.x + last.x) * inv25;
        float A1 = (sy + 12.f * first.y + last.y) * inv25;
        float A2 = (sz + 12.f * first.z + last.z) * inv25;
        float A3 = (sw + 12.f * first.w + last.w) * inv25;
        float D0 = (last.x - first.x) * inv25;
        float D1 = (last.y - first.y) * inv25;
        float D2 = (last.z - first.z) * inv25;
        float D3 = (last.w - first.w) * inv25;
        h2 t0, t1, t2, t3, t4, z;
        t0[0] = (_Float16)A0; t0[1] = (_Float16)A1;
        t1[0] = (_Float16)A2; t1[1] = (_Float16)A3;
        t2[0] = (_Float16)D0; t2[1] = (_Float16)D1;
        t3[0] = (_Float16)D2; t3[1] = (_Float16)D3;
        t4[0] = (_Float16)1.f; t4[1] = (_Float16)0.f;
        z[0] = (_Float16)0.f; z[1] = (_Float16)0.f;
        X2[24] = t0; X2[25] = t1; X2[26] = t2; X2[27] = t3;
        X2[28] = t4; X2[29] = z; X2[30] = z; X2[31] = z;
    }
    {
        const float2* xf2 = (const float2*)X2;
#pragma unroll
        for (int j = 0; j < 16; ++j) As2[17 * tid + j] = xf2[j];
    }
    __syncthreads();

    // Phase 2: B-operand (pixel) fragments. Wave: class rcls, groups ghalf*4..+3.
    int quad = L >> 4, nlane = L & 15;
    int rcls = wv & 3, ghalf = wv >> 2;
    int cls = rh * 4 + rcls;
    f16x8 pf[4][2];
#pragma unroll
    for (int g = 0; g < 4; ++g) {
        int G = ghalf * 4 + g;
        int p = 64 * G + 32 * (nlane >> 3) + 4 * (nlane & 7) + rcls;
        int base = 17 * p;
#pragma unroll
        for (int ks = 0; ks < 2; ++ks) {
            F2H8 u;
            u.f.lo = As2[base + ks * 8 + quad * 2];
            u.f.hi = As2[base + ks * 8 + quad * 2 + 1];
            pf[g][ks] = u.h8;
        }
    }

    // Per-lane geometry for fold masks and stores.
    int rp = nlane >> 3, ci = nlane & 7;
    int wwp = wh * 8 + ci;
    bool okw0 = wwp <= 14, okw1 = wwp >= 1;  // dj=0 / dj=1
    // float index within (b,to) image: h*256 + w*4 + c
    int colf = (wh * 32 + 4 * ci + rcls) * 4 + quad;  // lane-const col+channel
    float* outb = out + (size_t)bb * 12 * 16384;

    // Phase 3: to in halves of 6 (wf = 48 VGPRs); direct masked-fold stores.
#pragma unroll 1
    for (int toh = 0; toh < 2; ++toh) {
        f16x8 wf[6][2];
#pragma unroll
        for (int tt = 0; tt < 6; ++tt)
#pragma unroll
            for (int ks = 0; ks < 2; ++ks) {
                F2H8 u;
                const float4 v = PWF[((size_t)(cls * 12 + toh * 6 + tt) * 2 + ks) * 64 + L];
                u.f.lo = make_float2(v.x, v.y);
                u.f.hi = make_float2(v.z, v.w);
                wf[tt][ks] = u.h8;
            }
#pragma unroll
        for (int tt = 0; tt < 6; ++tt) {
            int to = toh * 6 + tt;
#pragma unroll
            for (int g = 0; g < 4; ++g) {
                int G = ghalf * 4 + g;
                f32x4 d = {0.f, 0.f, 0.f, 0.f};
                d = __builtin_amdgcn_mfma_f32_16x16x32_f16(wf[tt][0], pf[g][0], d, 0, 0, 0);
                d = __builtin_amdgcn_mfma_f32_16x16x32_f16(wf[tt][1], pf[g][1], d, 0, 0, 0);
                int hhl = 2 * G + rp;
                bool okh0 = hhl <= 14, okh1 = hhl >= 1;
                float v = ((okh0 && okw0) ? d[0] : 0.f)
                        + ((okh0 && okw1) ? d[1] : 0.f)
                        + ((okh1 && okw0) ? d[2] : 0.f)
                        + ((okh1 && okw1) ? d[3] : 0.f);
                int h2i = 4 * hhl + rh;
                outb[(size_t)to * 16384 + h2i * 256 + colf] = v;
            }
        }
    }
}

extern "C" void kernel_launch(void* const* d_in, const int* in_sizes, int n_in,
                              void* d_out, int out_size, void* d_ws, size_t ws_size,
                              hipStream_t stream) {
    const float* x = (const float*)d_in[0];
    const float* w_s = (const float*)d_in[1];
    const float* b_s = (const float*)d_in[2];
    const float* w_t = (const float*)d_in[3];
    const float* b_t = (const float*)d_in[4];
    float* out = (float*)d_out;
    void* PWF = d_ws;  // 192*2*64*16 = 393216 B

    pack_frags<<<192, 256, 0, stream>>>(w_s, b_s, w_t, b_t, (uint2*)PWF);
    dlinear_mfma<<<32 * 4 * 2, 512, 0, stream>>>(x, (const float4*)PWF, out);
}